// Round 1
// baseline (306.546 us; speedup 1.0000x reference)
//
#include <hip/hip_runtime.h>

typedef unsigned short u16;
typedef unsigned int   u32;
typedef unsigned long long u64;
typedef __attribute__((ext_vector_type(4))) float f32x4;
typedef __attribute__((ext_vector_type(8))) short bf16x8;
typedef __attribute__((ext_vector_type(4))) u16  u16x4;
typedef __attribute__((ext_vector_type(8))) u16  u16x8;
typedef __attribute__((ext_vector_type(4))) u32  u32x4;

#define B_  32
#define TQ  1024
#define TK  1024
#define FG  128
#define DV  256

__device__ __forceinline__ u16 f2bf(float x) {
    union { float f; u32 u; } v; v.f = x;
    u32 r = v.u + 0x7fffu + ((v.u >> 16) & 1u);   // RNE
    return (u16)(r >> 16);
}
__device__ __forceinline__ float bf2f(u16 h) {
    union { u32 u; float f; } v; v.u = ((u32)h) << 16;
    return v.f;
}

// ---------------------------------------------------------------------------
// Split+transpose weights: Wq[512,128] -> WqT hi/lo [128,512]; Wk[256,128] -> [128,256]
__global__ void prep_w(const float* __restrict__ Wq, const float* __restrict__ Wk,
                       u16* __restrict__ wqh, u16* __restrict__ wql,
                       u16* __restrict__ wkh, u16* __restrict__ wkl)
{
    const int t = blockIdx.x * 256 + threadIdx.x;
    if (t < 128 * 512) {
        const int n = t >> 9, k = t & 511;
        const float x = Wq[k * FG + n];
        const u16 h = f2bf(x);
        wqh[t] = h; wql[t] = f2bf(x - bf2f(h));
    } else {
        const int u = t - 128 * 512;
        const int n = u >> 8, k = u & 255;
        const float x = Wk[k * FG + n];
        const u16 h = f2bf(x);
        wkh[u] = h; wkl[u] = f2bf(x - bf2f(h));
    }
}

// ---------------------------------------------------------------------------
// v [32,1024,256] fp32 -> vT [32,256,1024] bf16
__global__ __launch_bounds__(256, 1)
void prep_v(const float* __restrict__ v, u16* __restrict__ vT)
{
    __shared__ u16 tile[64][72];
    const int tk0 = blockIdx.x * 64, d0 = blockIdx.y * 64, b = blockIdx.z;
    const int tid = threadIdx.x;
#pragma unroll
    for (int i = 0; i < 4; ++i) {
        const int f4 = i * 256 + tid;
        const int tkr = f4 >> 4, c4 = f4 & 15;
        f32x4 x = *reinterpret_cast<const f32x4*>(v + (u64)b * (TK * DV) + (u64)(tk0 + tkr) * DV + d0 + c4 * 4);
#pragma unroll
        for (int j = 0; j < 4; ++j) tile[tkr][c4 * 4 + j] = f2bf(x[j]);
    }
    __syncthreads();
#pragma unroll
    for (int i = 0; i < 2; ++i) {
        const int idx = i * 256 + tid;
        const int dr = idx >> 3, c8 = idx & 7;
        u16x8 o;
#pragma unroll
        for (int j = 0; j < 8; ++j) o[j] = tile[c8 * 8 + j][dr];
        *reinterpret_cast<u16x8*>(vT + (u64)b * (DV * TK) + (u64)(d0 + dr) * TK + tk0 + c8 * 8) = o;
    }
}

// ---------------------------------------------------------------------------
// Projection GEMM with split-bf16 (3-term) MFMA.
// X [M,K] fp32 @ WT[k][n] (stored as WT_hi/lo [128,K] bf16) -> out hi/lo [M,128] bf16, scaled.
// grid.x = M/64, 256 threads (4 waves, 2x2), BK=128.
__global__ __launch_bounds__(256, 1)
void proj_kernel(const float* __restrict__ X, const u16* __restrict__ WTh,
                 const u16* __restrict__ WTl, u16* __restrict__ Oh,
                 u16* __restrict__ Ol, const int K, const float scale)
{
    __shared__ char qs[32768];
    char* qsh = qs;
    char* qsl = qs + 16384;
    const int tid = threadIdx.x;
    const int wid = tid >> 6, lane = tid & 63;
    const int l16 = lane & 15, l4 = lane >> 4;
    const int wm = wid >> 1, wn = wid & 1;
    const int rowbase = blockIdx.x * 64;

    f32x4 acc[2][4] = {};
    const int nchunks = K >> 7;
    for (int kc = 0; kc < nchunks; ++kc) {
        if (kc) __syncthreads();
        // stage [64 rows][128 k] fp32 -> split hi/lo into swizzled LDS
#pragma unroll
        for (int i = 0; i < 8; ++i) {
            const int f4 = i * 256 + tid;
            const int r = f4 >> 5, c4 = f4 & 31;
            f32x4 x = *reinterpret_cast<const f32x4*>(X + (u64)(rowbase + r) * K + kc * 128 + c4 * 4);
            u16x4 hv, lv;
#pragma unroll
            for (int j = 0; j < 4; ++j) {
                const u16 h = f2bf(x[j]);
                hv[j] = h;
                lv[j] = f2bf(x[j] - bf2f(h));
            }
            const u32 a = r * 256 + ((u32)(c4 * 8) ^ ((r & 7) << 4));
            *reinterpret_cast<u16x4*>(qsh + a) = hv;
            *reinterpret_cast<u16x4*>(qsl + a) = lv;
        }
        __syncthreads();
#pragma unroll
        for (int kk = 0; kk < 4; ++kk) {
            bf16x8 ah[2], al[2];
#pragma unroll
            for (int mf = 0; mf < 2; ++mf) {
                const int r = wm * 32 + mf * 16 + l16;
                const u32 kb = kk * 64 + l4 * 16;
                const u32 a = r * 256 + (kb ^ ((u32)(r & 7) << 4));
                ah[mf] = *reinterpret_cast<const bf16x8*>(qsh + a);
                al[mf] = *reinterpret_cast<const bf16x8*>(qsl + a);
            }
#pragma unroll
            for (int nf = 0; nf < 4; ++nf) {
                const int col = wn * 64 + nf * 16 + l16;
                const u64 off = (u64)col * K + kc * 128 + kk * 32 + l4 * 8;
                bf16x8 bh = *reinterpret_cast<const bf16x8*>(WTh + off);
                bf16x8 bl = *reinterpret_cast<const bf16x8*>(WTl + off);
#pragma unroll
                for (int mf = 0; mf < 2; ++mf) {
                    acc[mf][nf] = __builtin_amdgcn_mfma_f32_16x16x32_bf16(ah[mf], bh, acc[mf][nf], 0, 0, 0);
                    acc[mf][nf] = __builtin_amdgcn_mfma_f32_16x16x32_bf16(ah[mf], bl, acc[mf][nf], 0, 0, 0);
                    acc[mf][nf] = __builtin_amdgcn_mfma_f32_16x16x32_bf16(al[mf], bh, acc[mf][nf], 0, 0, 0);
                }
            }
        }
    }
    // epilogue: scale, split, store
#pragma unroll
    for (int mf = 0; mf < 2; ++mf)
#pragma unroll
        for (int nf = 0; nf < 4; ++nf)
#pragma unroll
            for (int r = 0; r < 4; ++r) {
                const int row = rowbase + wm * 32 + mf * 16 + l4 * 4 + r;
                const int col = wn * 64 + nf * 16 + l16;
                const float xv = acc[mf][nf][r] * scale;
                const u16 h = f2bf(xv);
                Oh[(u64)row * FG + col] = h;
                Ol[(u64)row * FG + col] = f2bf(xv - bf2f(h));
            }
}

// ---------------------------------------------------------------------------
// Fused scores + mask + softmax + attn-write + PV.
// grid (32 q-tiles, 32 batches), 512 threads (8 waves). Per block: 32 Q rows.
// Wave w owns score columns [w*128, w*128+128).
__global__ __launch_bounds__(512, 1)
void attn_kernel(const u16* __restrict__ qp_hi, const u16* __restrict__ qp_lo,
                 const u16* __restrict__ kp_hi, const u16* __restrict__ kp_lo,
                 const u16* __restrict__ vT, const int* __restrict__ mask,
                 float* __restrict__ attn_out, float* __restrict__ ctx_out)
{
    extern __shared__ char smem[];
    char* qsh = smem;                        // [32][128] bf16 swizzled, 8KB
    char* qsl = smem + 8192;                 // 8KB
    char* as_ = smem + 16384;                // attn bf16 [32][1024] swizzled, 64KB
    float* red     = (float*)(smem + 16384 + 65536);  // [8][32]
    float* rowstat = red + 256;              // [0..31]=rowmax, [32..63]=1/Z

    const int qt = blockIdx.x, b = blockIdx.y;
    const int row0 = qt * 32;
    const int tid = threadIdx.x;
    const int wid = tid >> 6;
    const int lane = tid & 63;
    const int l16 = lane & 15;
    const int l4  = lane >> 4;

    // ---- stage qp tile (32 x 128, hi+lo) ----
    {
        const int t8 = tid * 8;
        const int r = t8 >> 7, c = t8 & 127;
        const u64 g = (u64)(b * TQ + row0 + r) * FG + c;
        u32x4 vh = *reinterpret_cast<const u32x4*>(qp_hi + g);
        u32x4 vl = *reinterpret_cast<const u32x4*>(qp_lo + g);
        const u32 a = r * 256 + ((u32)(c * 2) ^ ((r & 7) << 4));
        *reinterpret_cast<u32x4*>(qsh + a) = vh;
        *reinterpret_cast<u32x4*>(qsl + a) = vl;
    }
    __syncthreads();

    // ---- scores (3-term split-bf16 MFMA) ----
    f32x4 acc[2][8] = {};
    const u16* kpbh = kp_hi + (u64)b * TK * FG;
    const u16* kpbl = kp_lo + (u64)b * TK * FG;

#pragma unroll
    for (int kk = 0; kk < 4; ++kk) {
        bf16x8 ah[2], al[2];
#pragma unroll
        for (int mf = 0; mf < 2; ++mf) {
            const int r = mf * 16 + l16;
            const u32 kb = kk * 64 + l4 * 16;
            const u32 a = r * 256 + (kb ^ ((u32)(r & 7) << 4));
            ah[mf] = *reinterpret_cast<const bf16x8*>(qsh + a);
            al[mf] = *reinterpret_cast<const bf16x8*>(qsl + a);
        }
#pragma unroll
        for (int nf = 0; nf < 8; ++nf) {
            const int col = wid * 128 + nf * 16 + l16;
            const u64 off = (u64)col * FG + kk * 32 + l4 * 8;
            bf16x8 bh = *reinterpret_cast<const bf16x8*>(kpbh + off);
            bf16x8 bl = *reinterpret_cast<const bf16x8*>(kpbl + off);
#pragma unroll
            for (int mf = 0; mf < 2; ++mf) {
                acc[mf][nf] = __builtin_amdgcn_mfma_f32_16x16x32_bf16(ah[mf], bh, acc[mf][nf], 0, 0, 0);
                acc[mf][nf] = __builtin_amdgcn_mfma_f32_16x16x32_bf16(ah[mf], bl, acc[mf][nf], 0, 0, 0);
                acc[mf][nf] = __builtin_amdgcn_mfma_f32_16x16x32_bf16(al[mf], bh, acc[mf][nf], 0, 0, 0);
            }
        }
    }

    // ---- mask ----
    const int* mrow = mask + ((u64)b * TQ + row0) * TK;
#pragma unroll
    for (int mf = 0; mf < 2; ++mf)
#pragma unroll
        for (int r = 0; r < 4; ++r) {
            const int row = mf * 16 + l4 * 4 + r;
#pragma unroll
            for (int nf = 0; nf < 8; ++nf) {
                const int col = wid * 128 + nf * 16 + l16;
                if (mrow[(u64)row * TK + col] == 0) acc[mf][nf][r] = -1e9f;
            }
        }

    // ---- row max (16-lane shuffle, then cross-wave via LDS) ----
#pragma unroll
    for (int mf = 0; mf < 2; ++mf)
#pragma unroll
        for (int r = 0; r < 4; ++r) {
            float m = acc[mf][0][r];
#pragma unroll
            for (int nf = 1; nf < 8; ++nf) m = fmaxf(m, acc[mf][nf][r]);
#pragma unroll
            for (int sh = 1; sh < 16; sh <<= 1) m = fmaxf(m, __shfl_xor(m, sh));
            if (l16 == 0) red[wid * 32 + mf * 16 + l4 * 4 + r] = m;
        }
    __syncthreads();
    if (tid < 32) {
        float m = red[tid];
#pragma unroll
        for (int w = 1; w < 8; ++w) m = fmaxf(m, red[w * 32 + tid]);
        rowstat[tid] = m;
    }
    __syncthreads();

    // ---- exp + row sum ----
#pragma unroll
    for (int mf = 0; mf < 2; ++mf)
#pragma unroll
        for (int r = 0; r < 4; ++r) {
            const int row = mf * 16 + l4 * 4 + r;
            const float m = rowstat[row];
            float s = 0.0f;
#pragma unroll
            for (int nf = 0; nf < 8; ++nf) {
                const float e = __expf(acc[mf][nf][r] - m);
                acc[mf][nf][r] = e;
                s += e;
            }
#pragma unroll
            for (int sh = 1; sh < 16; sh <<= 1) s += __shfl_xor(s, sh);
            if (l16 == 0) red[wid * 32 + row] = s;
        }
    __syncthreads();
    if (tid < 32) {
        float z = red[tid];
#pragma unroll
        for (int w = 1; w < 8; ++w) z += red[w * 32 + tid];
        rowstat[32 + tid] = 1.0f / z;
    }
    __syncthreads();

    // ---- normalize: write attn fp32 to global, bf16 to swizzled LDS ----
    float* aout = attn_out + ((u64)b * TQ + row0) * TK;
#pragma unroll
    for (int mf = 0; mf < 2; ++mf)
#pragma unroll
        for (int r = 0; r < 4; ++r) {
            const int row = mf * 16 + l4 * 4 + r;
            const float rz = rowstat[32 + row];
#pragma unroll
            for (int nf = 0; nf < 8; ++nf) {
                const int col = wid * 128 + nf * 16 + l16;
                const float aval = acc[mf][nf][r] * rz;
                aout[(u64)row * TK + col] = aval;
                const u32 cb = (u32)(col * 2);
                *reinterpret_cast<u16*>(as_ + row * 2048 + (cb ^ ((u32)(row & 7) << 4))) = f2bf(aval);
            }
        }
    __syncthreads();

    // ---- PV: ctx[32,256] = attn[32,1024] @ v[1024,256]; wave w owns d-cols [w*32, w*32+32) ----
    f32x4 acc2[2][2] = {};
    const u16* vTb = vT + (u64)b * DV * TK;
    for (int ks = 0; ks < 32; ++ks) {
        bf16x8 pa[2];
#pragma unroll
        for (int mf = 0; mf < 2; ++mf) {
            const int r = mf * 16 + l16;
            const u32 kb = ks * 64 + l4 * 16;
            pa[mf] = *reinterpret_cast<const bf16x8*>(as_ + r * 2048 + (kb ^ ((u32)(r & 7) << 4)));
        }
#pragma unroll
        for (int nf2 = 0; nf2 < 2; ++nf2) {
            const int d = wid * 32 + nf2 * 16 + l16;
            bf16x8 bv = *reinterpret_cast<const bf16x8*>(vTb + (u64)d * TK + ks * 32 + l4 * 8);
#pragma unroll
            for (int mf = 0; mf < 2; ++mf)
                acc2[mf][nf2] = __builtin_amdgcn_mfma_f32_16x16x32_bf16(pa[mf], bv, acc2[mf][nf2], 0, 0, 0);
        }
    }
    float* cout = ctx_out + ((u64)b * TQ + row0) * DV;
#pragma unroll
    for (int mf = 0; mf < 2; ++mf)
#pragma unroll
        for (int nf2 = 0; nf2 < 2; ++nf2)
#pragma unroll
            for (int r = 0; r < 4; ++r) {
                const int row = mf * 16 + l4 * 4 + r;
                const int d = wid * 32 + nf2 * 16 + l16;
                cout[(u64)row * DV + d] = acc2[mf][nf2][r];
            }
}

// ---------------------------------------------------------------------------
extern "C" void kernel_launch(void* const* d_in, const int* in_sizes, int n_in,
                              void* d_out, int out_size, void* d_ws, size_t ws_size,
                              hipStream_t stream)
{
    const float* q    = (const float*)d_in[0];
    const float* k    = (const float*)d_in[1];
    const float* v    = (const float*)d_in[2];
    const int*   mask = (const int*)d_in[3];
    const float* Wq   = (const float*)d_in[4];
    const float* Wk   = (const float*)d_in[5];

    float* ctx  = (float*)d_out;
    float* attn = ctx + (u64)B_ * TQ * DV;

    u16* p = (u16*)d_ws;
    u16* qp_hi = p; p += (u64)B_ * TQ * FG;
    u16* qp_lo = p; p += (u64)B_ * TQ * FG;
    u16* kp_hi = p; p += (u64)B_ * TK * FG;
    u16* kp_lo = p; p += (u64)B_ * TK * FG;
    u16* vTb   = p; p += (u64)B_ * DV * TK;
    u16* wqh = p; p += 128 * 512;
    u16* wql = p; p += 128 * 512;
    u16* wkh = p; p += 128 * 256;
    u16* wkl = p; p += 128 * 256;

    hipLaunchKernelGGL(prep_w, dim3(384), dim3(256), 0, stream, Wq, Wk, wqh, wql, wkh, wkl);
    hipLaunchKernelGGL(prep_v, dim3(16, 4, 32), dim3(256), 0, stream, v, vTb);
    hipLaunchKernelGGL(proj_kernel, dim3(512), dim3(256), 0, stream, q, wqh, wql, qp_hi, qp_lo, 512, 0.0625f);
    hipLaunchKernelGGL(proj_kernel, dim3(512), dim3(256), 0, stream, k, wkh, wkl, kp_hi, kp_lo, 256, 1.0f);

    const int lds = 16384 + 65536 + 256 * 4 + 64 * 4;
    (void)hipFuncSetAttribute(reinterpret_cast<const void*>(attn_kernel),
                              hipFuncAttributeMaxDynamicSharedMemorySize, lds);
    hipLaunchKernelGGL(attn_kernel, dim3(32, 32), dim3(512), lds, stream,
                       qp_hi, qp_lo, kp_hi, kp_lo, vTb, mask, attn, ctx);
}

// Round 2
// 293.698 us; speedup vs baseline: 1.0437x; 1.0437x over previous
//
#include <hip/hip_runtime.h>

typedef unsigned short u16;
typedef unsigned int   u32;
typedef unsigned long long u64;
typedef __attribute__((ext_vector_type(4))) float f32x4;
typedef __attribute__((ext_vector_type(8))) short bf16x8;
typedef __attribute__((ext_vector_type(4))) u16  u16x4;
typedef __attribute__((ext_vector_type(8))) u16  u16x8;
typedef __attribute__((ext_vector_type(4))) u32  u32x4;

#define B_  32
#define TQ  1024
#define TK  1024
#define FG  128
#define DV  256

__device__ __forceinline__ u16 f2bf(float x) {
    union { float f; u32 u; } v; v.f = x;
    u32 r = v.u + 0x7fffu + ((v.u >> 16) & 1u);   // RNE
    return (u16)(r >> 16);
}
__device__ __forceinline__ float bf2f(u16 h) {
    union { u32 u; float f; } v; v.u = ((u32)h) << 16;
    return v.f;
}

// ---------------------------------------------------------------------------
// Split+transpose weights: Wq[512,128] -> WqT hi/lo [128,512]; Wk[256,128] -> [128,256]
__global__ void prep_w(const float* __restrict__ Wq, const float* __restrict__ Wk,
                       u16* __restrict__ wqh, u16* __restrict__ wql,
                       u16* __restrict__ wkh, u16* __restrict__ wkl)
{
    const int t = blockIdx.x * 256 + threadIdx.x;
    if (t < 128 * 512) {
        const int n = t >> 9, k = t & 511;
        const float x = Wq[k * FG + n];
        const u16 h = f2bf(x);
        wqh[t] = h; wql[t] = f2bf(x - bf2f(h));
    } else {
        const int u = t - 128 * 512;
        const int n = u >> 8, k = u & 255;
        const float x = Wk[k * FG + n];
        const u16 h = f2bf(x);
        wkh[u] = h; wkl[u] = f2bf(x - bf2f(h));
    }
}

// ---------------------------------------------------------------------------
// v [32,1024,256] fp32 -> vT [32,256,1024] bf16
__global__ __launch_bounds__(256, 1)
void prep_v(const float* __restrict__ v, u16* __restrict__ vT)
{
    __shared__ u16 tile[64][72];
    const int tk0 = blockIdx.x * 64, d0 = blockIdx.y * 64, b = blockIdx.z;
    const int tid = threadIdx.x;
#pragma unroll
    for (int i = 0; i < 4; ++i) {
        const int f4 = i * 256 + tid;
        const int tkr = f4 >> 4, c4 = f4 & 15;
        f32x4 x = *reinterpret_cast<const f32x4*>(v + (u64)b * (TK * DV) + (u64)(tk0 + tkr) * DV + d0 + c4 * 4);
#pragma unroll
        for (int j = 0; j < 4; ++j) tile[tkr][c4 * 4 + j] = f2bf(x[j]);
    }
    __syncthreads();
#pragma unroll
    for (int i = 0; i < 2; ++i) {
        const int idx = i * 256 + tid;
        const int dr = idx >> 3, c8 = idx & 7;
        u16x8 o;
#pragma unroll
        for (int j = 0; j < 8; ++j) o[j] = tile[c8 * 8 + j][dr];
        *reinterpret_cast<u16x8*>(vT + (u64)b * (DV * TK) + (u64)(d0 + dr) * TK + tk0 + c8 * 8) = o;
    }
}

// ---------------------------------------------------------------------------
// Projection GEMM with split-bf16 (3-term) MFMA.
__global__ __launch_bounds__(256, 1)
void proj_kernel(const float* __restrict__ X, const u16* __restrict__ WTh,
                 const u16* __restrict__ WTl, u16* __restrict__ Oh,
                 u16* __restrict__ Ol, const int K, const float scale)
{
    __shared__ char qs[32768];
    char* qsh = qs;
    char* qsl = qs + 16384;
    const int tid = threadIdx.x;
    const int wid = tid >> 6, lane = tid & 63;
    const int l16 = lane & 15, l4 = lane >> 4;
    const int wm = wid >> 1, wn = wid & 1;
    const int rowbase = blockIdx.x * 64;

    f32x4 acc[2][4] = {};
    const int nchunks = K >> 7;
    for (int kc = 0; kc < nchunks; ++kc) {
        if (kc) __syncthreads();
#pragma unroll
        for (int i = 0; i < 8; ++i) {
            const int f4 = i * 256 + tid;
            const int r = f4 >> 5, c4 = f4 & 31;
            f32x4 x = *reinterpret_cast<const f32x4*>(X + (u64)(rowbase + r) * K + kc * 128 + c4 * 4);
            u16x4 hv, lv;
#pragma unroll
            for (int j = 0; j < 4; ++j) {
                const u16 h = f2bf(x[j]);
                hv[j] = h;
                lv[j] = f2bf(x[j] - bf2f(h));
            }
            const u32 a = r * 256 + ((u32)(c4 * 8) ^ ((r & 7) << 4));
            *reinterpret_cast<u16x4*>(qsh + a) = hv;
            *reinterpret_cast<u16x4*>(qsl + a) = lv;
        }
        __syncthreads();
#pragma unroll
        for (int kk = 0; kk < 4; ++kk) {
            bf16x8 ah[2], al[2];
#pragma unroll
            for (int mf = 0; mf < 2; ++mf) {
                const int r = wm * 32 + mf * 16 + l16;
                const u32 kb = kk * 64 + l4 * 16;
                const u32 a = r * 256 + (kb ^ ((u32)(r & 7) << 4));
                ah[mf] = *reinterpret_cast<const bf16x8*>(qsh + a);
                al[mf] = *reinterpret_cast<const bf16x8*>(qsl + a);
            }
#pragma unroll
            for (int nf = 0; nf < 4; ++nf) {
                const int col = wn * 64 + nf * 16 + l16;
                const u64 off = (u64)col * K + kc * 128 + kk * 32 + l4 * 8;
                bf16x8 bh = *reinterpret_cast<const bf16x8*>(WTh + off);
                bf16x8 bl = *reinterpret_cast<const bf16x8*>(WTl + off);
#pragma unroll
                for (int mf = 0; mf < 2; ++mf) {
                    acc[mf][nf] = __builtin_amdgcn_mfma_f32_16x16x32_bf16(ah[mf], bh, acc[mf][nf], 0, 0, 0);
                    acc[mf][nf] = __builtin_amdgcn_mfma_f32_16x16x32_bf16(ah[mf], bl, acc[mf][nf], 0, 0, 0);
                    acc[mf][nf] = __builtin_amdgcn_mfma_f32_16x16x32_bf16(al[mf], bh, acc[mf][nf], 0, 0, 0);
                }
            }
        }
    }
#pragma unroll
    for (int mf = 0; mf < 2; ++mf)
#pragma unroll
        for (int nf = 0; nf < 4; ++nf)
#pragma unroll
            for (int r = 0; r < 4; ++r) {
                const int row = rowbase + wm * 32 + mf * 16 + l4 * 4 + r;
                const int col = wn * 64 + nf * 16 + l16;
                const float xv = acc[mf][nf][r] * scale;
                const u16 h = f2bf(xv);
                Oh[(u64)row * FG + col] = h;
                Ol[(u64)row * FG + col] = f2bf(xv - bf2f(h));
            }
}

// ---------------------------------------------------------------------------
// Fused scores + mask + softmax + attn-write + PV.
// grid (32 q-tiles, 32 batches), 512 threads (8 waves). Per block: 32 Q rows.
// Wave w owns score columns [w*128, w*128+128).
// LDS: attn bf16 tile 64KB + reductions -> 66.8KB => 2 blocks/CU with VGPR<=128.
__global__ __launch_bounds__(512, 4)
void attn_kernel(const u16* __restrict__ qp_hi, const u16* __restrict__ qp_lo,
                 const u16* __restrict__ kp_hi, const u16* __restrict__ kp_lo,
                 const u16* __restrict__ vT, const int* __restrict__ mask,
                 float* __restrict__ attn_out, float* __restrict__ ctx_out)
{
    extern __shared__ char smem[];
    char* as_ = smem;                                 // attn bf16 [32][1024] swizzled, 64KB
    float* red     = (float*)(smem + 65536);          // [8][32]
    float* rowstat = red + 256;                       // [0..31]=rowmax, [32..63]=1/Z

    const int qt = blockIdx.x, b = blockIdx.y;
    const int row0 = qt * 32;
    const int tid = threadIdx.x;
    const int wid = tid >> 6;
    const int lane = tid & 63;
    const int l16 = lane & 15;
    const int l4  = lane >> 4;

    // ---- hoisted mask loads -> packed register bitmask (overlaps with QK^T) ----
    const int* mrow = mask + ((u64)b * TQ + row0) * TK;
    u32 mb0 = 0, mb1 = 0;
#pragma unroll
    for (int mf = 0; mf < 2; ++mf)
#pragma unroll
        for (int r = 0; r < 4; ++r) {
            const int row = mf * 16 + l4 * 4 + r;
#pragma unroll
            for (int nf = 0; nf < 8; ++nf) {
                const int col = wid * 128 + nf * 16 + l16;
                const int idx = mf * 32 + r * 8 + nf;
                const u32 bit = (mrow[(u64)row * TK + col] != 0) ? 1u : 0u;
                if (idx < 32) mb0 |= bit << idx; else mb1 |= bit << (idx - 32);
            }
        }

    // ---- scores (3-term split-bf16 MFMA); Q frags direct from global (L2-hot) ----
    f32x4 acc[2][8] = {};
    const u16* qph = qp_hi + (u64)(b * TQ + row0) * FG;
    const u16* qpl = qp_lo + (u64)(b * TQ + row0) * FG;
    const u16* kpbh = kp_hi + (u64)b * TK * FG;
    const u16* kpbl = kp_lo + (u64)b * TK * FG;

#pragma unroll
    for (int kk = 0; kk < 4; ++kk) {
        bf16x8 ah[2], al[2];
#pragma unroll
        for (int mf = 0; mf < 2; ++mf) {
            const u64 o = (u64)(mf * 16 + l16) * FG + kk * 32 + l4 * 8;
            ah[mf] = *reinterpret_cast<const bf16x8*>(qph + o);
            al[mf] = *reinterpret_cast<const bf16x8*>(qpl + o);
        }
#pragma unroll
        for (int nf = 0; nf < 8; ++nf) {
            const int col = wid * 128 + nf * 16 + l16;
            const u64 off = (u64)col * FG + kk * 32 + l4 * 8;
            bf16x8 bh = *reinterpret_cast<const bf16x8*>(kpbh + off);
            bf16x8 bl = *reinterpret_cast<const bf16x8*>(kpbl + off);
#pragma unroll
            for (int mf = 0; mf < 2; ++mf) {
                acc[mf][nf] = __builtin_amdgcn_mfma_f32_16x16x32_bf16(ah[mf], bh, acc[mf][nf], 0, 0, 0);
                acc[mf][nf] = __builtin_amdgcn_mfma_f32_16x16x32_bf16(ah[mf], bl, acc[mf][nf], 0, 0, 0);
                acc[mf][nf] = __builtin_amdgcn_mfma_f32_16x16x32_bf16(al[mf], bh, acc[mf][nf], 0, 0, 0);
            }
        }
    }

    // ---- mask apply (pure ALU) ----
#pragma unroll
    for (int mf = 0; mf < 2; ++mf)
#pragma unroll
        for (int r = 0; r < 4; ++r)
#pragma unroll
            for (int nf = 0; nf < 8; ++nf) {
                const int idx = mf * 32 + r * 8 + nf;
                const u32 bit = (idx < 32) ? (mb0 >> idx) : (mb1 >> (idx - 32));
                if (!(bit & 1)) acc[mf][nf][r] = -1e9f;
            }

    // ---- row max ----
#pragma unroll
    for (int mf = 0; mf < 2; ++mf)
#pragma unroll
        for (int r = 0; r < 4; ++r) {
            float m = acc[mf][0][r];
#pragma unroll
            for (int nf = 1; nf < 8; ++nf) m = fmaxf(m, acc[mf][nf][r]);
#pragma unroll
            for (int sh = 1; sh < 16; sh <<= 1) m = fmaxf(m, __shfl_xor(m, sh));
            if (l16 == 0) red[wid * 32 + mf * 16 + l4 * 4 + r] = m;
        }
    __syncthreads();
    if (tid < 32) {
        float m = red[tid];
#pragma unroll
        for (int w = 1; w < 8; ++w) m = fmaxf(m, red[w * 32 + tid]);
        rowstat[tid] = m;
    }
    __syncthreads();

    // ---- exp + row sum ----
#pragma unroll
    for (int mf = 0; mf < 2; ++mf)
#pragma unroll
        for (int r = 0; r < 4; ++r) {
            const int row = mf * 16 + l4 * 4 + r;
            const float m = rowstat[row];
            float s = 0.0f;
#pragma unroll
            for (int nf = 0; nf < 8; ++nf) {
                const float e = __expf(acc[mf][nf][r] - m);
                acc[mf][nf][r] = e;
                s += e;
            }
#pragma unroll
            for (int sh = 1; sh < 16; sh <<= 1) s += __shfl_xor(s, sh);
            if (l16 == 0) red[wid * 32 + row] = s;
        }
    __syncthreads();
    if (tid < 32) {
        float z = red[tid];
#pragma unroll
        for (int w = 1; w < 8; ++w) z += red[w * 32 + tid];
        rowstat[32 + tid] = 1.0f / z;
    }
    __syncthreads();

    // ---- normalize: write attn fp32 to global, bf16 to swizzled LDS ----
    float* aout = attn_out + ((u64)b * TQ + row0) * TK;
#pragma unroll
    for (int mf = 0; mf < 2; ++mf)
#pragma unroll
        for (int r = 0; r < 4; ++r) {
            const int row = mf * 16 + l4 * 4 + r;
            const float rz = rowstat[32 + row];
#pragma unroll
            for (int nf = 0; nf < 8; ++nf) {
                const int col = wid * 128 + nf * 16 + l16;
                const float aval = acc[mf][nf][r] * rz;
                aout[(u64)row * TK + col] = aval;
                const u32 cb = (u32)(col * 2);
                *reinterpret_cast<u16*>(as_ + row * 2048 + (cb ^ ((u32)(row & 7) << 4))) = f2bf(aval);
            }
        }
    __syncthreads();

    // ---- PV: ctx[32,256] = attn[32,1024] @ v[1024,256]; wave w owns d-cols [w*32, w*32+32) ----
    f32x4 acc2[2][2] = {};
    const u16* vTb = vT + (u64)b * DV * TK;
#pragma unroll 4
    for (int ks = 0; ks < 32; ++ks) {
        bf16x8 pa[2];
#pragma unroll
        for (int mf = 0; mf < 2; ++mf) {
            const int r = mf * 16 + l16;
            const u32 kb = ks * 64 + l4 * 16;
            pa[mf] = *reinterpret_cast<const bf16x8*>(as_ + r * 2048 + (kb ^ ((u32)(r & 7) << 4)));
        }
#pragma unroll
        for (int nf2 = 0; nf2 < 2; ++nf2) {
            const int d = wid * 32 + nf2 * 16 + l16;
            bf16x8 bv = *reinterpret_cast<const bf16x8*>(vTb + (u64)d * TK + ks * 32 + l4 * 8);
#pragma unroll
            for (int mf = 0; mf < 2; ++mf)
                acc2[mf][nf2] = __builtin_amdgcn_mfma_f32_16x16x32_bf16(pa[mf], bv, acc2[mf][nf2], 0, 0, 0);
        }
    }
    float* cout = ctx_out + ((u64)b * TQ + row0) * DV;
#pragma unroll
    for (int mf = 0; mf < 2; ++mf)
#pragma unroll
        for (int nf2 = 0; nf2 < 2; ++nf2)
#pragma unroll
            for (int r = 0; r < 4; ++r) {
                const int row = mf * 16 + l4 * 4 + r;
                const int d = wid * 32 + nf2 * 16 + l16;
                cout[(u64)row * DV + d] = acc2[mf][nf2][r];
            }
}

// ---------------------------------------------------------------------------
extern "C" void kernel_launch(void* const* d_in, const int* in_sizes, int n_in,
                              void* d_out, int out_size, void* d_ws, size_t ws_size,
                              hipStream_t stream)
{
    const float* q    = (const float*)d_in[0];
    const float* k    = (const float*)d_in[1];
    const float* v    = (const float*)d_in[2];
    const int*   mask = (const int*)d_in[3];
    const float* Wq   = (const float*)d_in[4];
    const float* Wk   = (const float*)d_in[5];

    float* ctx  = (float*)d_out;
    float* attn = ctx + (u64)B_ * TQ * DV;

    u16* p = (u16*)d_ws;
    u16* qp_hi = p; p += (u64)B_ * TQ * FG;
    u16* qp_lo = p; p += (u64)B_ * TQ * FG;
    u16* kp_hi = p; p += (u64)B_ * TK * FG;
    u16* kp_lo = p; p += (u64)B_ * TK * FG;
    u16* vTb   = p; p += (u64)B_ * DV * TK;
    u16* wqh = p; p += 128 * 512;
    u16* wql = p; p += 128 * 512;
    u16* wkh = p; p += 128 * 256;
    u16* wkl = p; p += 128 * 256;

    hipLaunchKernelGGL(prep_w, dim3(384), dim3(256), 0, stream, Wq, Wk, wqh, wql, wkh, wkl);
    hipLaunchKernelGGL(prep_v, dim3(16, 4, 32), dim3(256), 0, stream, v, vTb);
    hipLaunchKernelGGL(proj_kernel, dim3(512), dim3(256), 0, stream, q, wqh, wql, qp_hi, qp_lo, 512, 0.0625f);
    hipLaunchKernelGGL(proj_kernel, dim3(512), dim3(256), 0, stream, k, wkh, wkl, kp_hi, kp_lo, 256, 1.0f);

    const int lds = 65536 + 256 * 4 + 64 * 4;
    (void)hipFuncSetAttribute(reinterpret_cast<const void*>(attn_kernel),
                              hipFuncAttributeMaxDynamicSharedMemorySize, lds);
    hipLaunchKernelGGL(attn_kernel, dim3(32, 32), dim3(512), lds, stream,
                       qp_hi, qp_lo, kp_hi, kp_lo, vTb, mask, attn, ctx);
}